// Round 6
// baseline (178.053 us; speedup 1.0000x reference)
//
#include <hip/hip_runtime.h>

#define NB 16
#define NC 128
#define NH 8192
#define EPSN 1e-5f

typedef __attribute__((ext_vector_type(8))) short short8;
typedef __attribute__((ext_vector_type(4))) float f32x4;

__device__ inline unsigned short f2bf(float f) {
  unsigned int u = __builtin_bit_cast(unsigned int, f);
  u = u + 0x7FFFu + ((u >> 16) & 1u);
  return (unsigned short)(u >> 16);
}

// ---------------------------------------------------------------------------
// Fused: alpha = sigmoid(fc(cat(corr,coh))); agg = corr - alpha*feats;
// per-(b,c) sum/sumsq of agg for InstanceNorm1.
// Block = (b, 128-h tile). Thread = (cpart 0..7, hq 0..31) -> 16 c x 4 h.
// NO register stash of corr (round-5 spill bug): pass 2 RE-READS corr —
// the tile was fetched one barrier earlier, so it comes from L2/L3.
// Both passes use an explicit ping-pong (4-cc chunks, 8 float4 loads in
// flight per thread, all compile-time indexed).
__global__ __launch_bounds__(256) void alphaagg_kernel(
    const float* __restrict__ corr, const float* __restrict__ coh,
    const float* __restrict__ feats, const float* __restrict__ fcw,
    const float* __restrict__ fcb, float* __restrict__ agg,
    float* __restrict__ stats) {
  __shared__ float plog[8][128];
  __shared__ float salpha[128];
  const int t = threadIdx.x;
  const int b = blockIdx.x >> 6;
  const int h0 = (blockIdx.x & 63) << 7;  // 128-h tile
  const int cpart = t >> 5;               // 0..7 (16 c each)
  const int hq = t & 31;                  // h = h0 + hq*4 + i
  const int hoff = h0 + hq * 4;

  const float* pcb = corr + ((size_t)(b * NC + cpart * 16) << 13) + hoff;
  const float* phb = coh + ((size_t)(b * NC + cpart * 16) << 13) + hoff;
  const float* pfb = feats + ((size_t)(b * NC + cpart * 16) << 13) + hoff;
  float* pab = agg + ((size_t)(b * NC + cpart * 16) << 13) + hoff;

  // fc weights for this thread's 16 channels (compile-time indexed)
  float fw0[16], fw1[16];
#pragma unroll
  for (int k = 0; k < 4; ++k) {
    *(float4*)&fw0[k * 4] = *(const float4*)(fcw + cpart * 16 + k * 4);
    *(float4*)&fw1[k * 4] = *(const float4*)(fcw + NC + cpart * 16 + k * 4);
  }

  // ---- pass 1: logit partials (ping-pong, no stash)
  float4 cr[2][4], ch[2][4];
#pragma unroll
  for (int u = 0; u < 4; ++u) {
    cr[0][u] = *(const float4*)(pcb + ((size_t)u << 13));
    ch[0][u] = *(const float4*)(phb + ((size_t)u << 13));
  }
  float4 lg = {0.f, 0.f, 0.f, 0.f};
#pragma unroll
  for (int g = 0; g < 4; ++g) {
    const int cur = g & 1, nxt = (g & 1) ^ 1;
    if (g < 3) {
#pragma unroll
      for (int u = 0; u < 4; ++u) {
        cr[nxt][u] = *(const float4*)(pcb + ((size_t)(g * 4 + 4 + u) << 13));
        ch[nxt][u] = *(const float4*)(phb + ((size_t)(g * 4 + 4 + u) << 13));
      }
    }
#pragma unroll
    for (int u = 0; u < 4; ++u) {
      const int cc = g * 4 + u;
      const float w0 = fw0[cc], w1 = fw1[cc];
      lg.x = fmaf(cr[cur][u].x, w0, fmaf(ch[cur][u].x, w1, lg.x));
      lg.y = fmaf(cr[cur][u].y, w0, fmaf(ch[cur][u].y, w1, lg.y));
      lg.z = fmaf(cr[cur][u].z, w0, fmaf(ch[cur][u].z, w1, lg.z));
      lg.w = fmaf(cr[cur][u].w, w0, fmaf(ch[cur][u].w, w1, lg.w));
    }
  }
  *(float4*)&plog[cpart][hq * 4] = lg;
  __syncthreads();

  // ---- reduce 8 partials, sigmoid
  if (t < 128) {
    float l = fcb[0];
#pragma unroll
    for (int p = 0; p < 8; ++p) l += plog[p][t];
    salpha[t] = 1.0f / (1.0f + __expf(-l));
  }
  __syncthreads();

  // ---- pass 2: agg = corr - alpha*feats (corr re-read: L2/L3 hit);
  //      write agg; per-c stats via 32-lane shuffle reduce.
  const float4 av = *(const float4*)&salpha[hq * 4];
  float4 c2[2][4], fr[2][4];
#pragma unroll
  for (int u = 0; u < 4; ++u) {
    c2[0][u] = *(const float4*)(pcb + ((size_t)u << 13));
    fr[0][u] = *(const float4*)(pfb + ((size_t)u << 13));
  }
#pragma unroll
  for (int g = 0; g < 4; ++g) {
    const int cur = g & 1, nxt = (g & 1) ^ 1;
    if (g < 3) {
#pragma unroll
      for (int u = 0; u < 4; ++u) {
        c2[nxt][u] = *(const float4*)(pcb + ((size_t)(g * 4 + 4 + u) << 13));
        fr[nxt][u] = *(const float4*)(pfb + ((size_t)(g * 4 + 4 + u) << 13));
      }
    }
#pragma unroll
    for (int u = 0; u < 4; ++u) {
      const int cc = g * 4 + u;
      float4 gg;
      gg.x = c2[cur][u].x - av.x * fr[cur][u].x;
      gg.y = c2[cur][u].y - av.y * fr[cur][u].y;
      gg.z = c2[cur][u].z - av.z * fr[cur][u].z;
      gg.w = c2[cur][u].w - av.w * fr[cur][u].w;
      *(float4*)(pab + ((size_t)cc << 13)) = gg;
      float s = (gg.x + gg.y) + (gg.z + gg.w);
      float q = fmaf(gg.x, gg.x, fmaf(gg.y, gg.y, fmaf(gg.z, gg.z, gg.w * gg.w)));
#pragma unroll
      for (int m = 1; m <= 16; m <<= 1) {  // reduce over 32 h-quads
        s += __shfl_xor(s, m);
        q += __shfl_xor(q, m);
      }
      if (hq == 0) {
        atomicAdd(&stats[(b * NC + cpart * 16 + cc) * 2], s);
        atomicAdd(&stats[(b * NC + cpart * 16 + cc) * 2 + 1], q);
      }
    }
  }
}

// ---------------------------------------------------------------------------
// Fold IN (per b,c) + analytic BN (per c) + gamma/beta into per-(b,c) affine.
__global__ void finalize_kernel(const float* __restrict__ stats,
                                const float* __restrict__ g,
                                const float* __restrict__ be,
                                float* __restrict__ scale,
                                float* __restrict__ shift) {
  int c = threadIdx.x;  // 128 threads, 1 block
  float mean[NB], rstd[NB];
  float bnacc = 0.f;
#pragma unroll
  for (int b = 0; b < NB; ++b) {
    float s = stats[(b * NC + c) * 2];
    float q = stats[(b * NC + c) * 2 + 1];
    float m = s * (1.f / NH);
    float v = fmaxf(q * (1.f / NH) - m * m, 0.f);
    float r = rsqrtf(v + EPSN);
    mean[b] = m;
    rstd[b] = r;
    bnacc += v * r * r;
  }
  float bnr = rsqrtf(bnacc * (1.f / NB) + EPSN);
  float gc = g[c], bec = be[c];
#pragma unroll
  for (int b = 0; b < NB; ++b) {
    float sc = rstd[b] * bnr * gc;
    scale[b * NC + c] = sc;
    shift[b * NC + c] = fmaf(-mean[b], sc, bec);
  }
}

// ---------------------------------------------------------------------------
// bf16-MFMA 1x1 conv with fused input affine+ReLU, tile-looped + pipelined.
//   Out[b,o,h] = sum_c relu(X[b,c,h]*scale[b,c]+shift[b,c]) * W[o,c] + bias[o]
// LDS layout (B-fragment order):
//   halfword idx = fragid*512 + sublane*8 + j
//   fragid = (h>>4)*4 + (c>>5), sublane = 16*((c>>3)&3) + (h&15), j = c&7
// XOR swizzle byte ^= ((byte>>7)&7)<<4 on BOTH ds_write and ds_read.
// Block = (b, 2 consecutive 64-h tiles). In-place safe: each block reads and
// writes only its own disjoint h-range.
template <bool DOSTATS>
__global__ __launch_bounds__(256) void conv_mfma_kernel(
    const float* X, const float* __restrict__ scale,
    const float* __restrict__ shift, const float* __restrict__ W,
    const float* __restrict__ bias, float* Out, float* __restrict__ stats) {
  __shared__ __align__(16) unsigned short sXf[8192];  // 16 frags x 1 KB
  __shared__ float ssum[NC], ssq[NC];
  const int t = threadIdx.x;
  const int b = blockIdx.x >> 6;             // 64 blocks per batch
  const int hbase = (blockIdx.x & 63) << 7;  // 128 h per block (2 tiles)
  const int lane = t & 63;
  const int wv = t >> 6;
  const int wo = wv >> 1;  // o-half: wo*64
  const int wh = wv & 1;   // h-half within tile: wh*32

  if (DOSTATS && t < NC) { ssum[t] = 0.f; ssq[t] = 0.f; }

  // staging ownership: 8 consecutive c x 4 consecutive h per thread
  const int cb = (t >> 4) << 3;  // 0,8,...,120
  const int hq = t & 15;         // local h = hq*4 + r
  const int fragw = ((hq >> 2) << 2) + (cb >> 5);
  const int sub0 = (((cb >> 3) & 3) << 4) + ((hq & 3) << 2);
  const unsigned swz = ((unsigned)(sub0 >> 3)) << 4;  // r-invariant
  const unsigned br = ((unsigned)(lane << 4)) ^ (((unsigned)(lane >> 3)) << 4);

  const float* Xb = X + ((size_t)(b * NC) << 13);
  float* Ob = Out + ((size_t)(b * NC) << 13);

  // ---- prologue: issue tile-0 loads first (critical path)
  float4 xv[8];
#pragma unroll
  for (int p = 0; p < 8; ++p)
    xv[p] = *(const float4*)(Xb + ((size_t)(cb + p) << 13) + hbase + hq * 4);

  float scv[8], shv[8];
#pragma unroll
  for (int p = 0; p < 8; ++p) {
    scv[p] = scale[b * NC + cb + p];
    shv[p] = shift[b * NC + cb + p];
  }

  // ---- W frags (A operand), loaded once per block
  short8 wfr[4][4];
  {
    const int orow = wo * 64 + (lane & 15);
    const int cbw = 8 * (lane >> 4);
#pragma unroll
    for (int m = 0; m < 4; ++m) {
#pragma unroll
      for (int k = 0; k < 4; ++k) {
        const float* p = W + (orow + m * 16) * NC + k * 32 + cbw;
        float4 lo = *(const float4*)p;
        float4 hi = *(const float4*)(p + 4);
        union { short8 s; unsigned short u[8]; } fr;
        fr.u[0] = f2bf(lo.x); fr.u[1] = f2bf(lo.y);
        fr.u[2] = f2bf(lo.z); fr.u[3] = f2bf(lo.w);
        fr.u[4] = f2bf(hi.x); fr.u[5] = f2bf(hi.y);
        fr.u[6] = f2bf(hi.z); fr.u[7] = f2bf(hi.w);
        wfr[m][k] = fr.s;
      }
    }
  }

  float as_[4][4], aq_[4][4];
  if (DOSTATS) {
#pragma unroll
    for (int m = 0; m < 4; ++m)
#pragma unroll
      for (int r = 0; r < 4; ++r) { as_[m][r] = 0.f; aq_[m][r] = 0.f; }
  }

  const int og = (lane >> 4) << 2;
  const int hcol = lane & 15;

  for (int tt = 0; tt < 2; ++tt) {
    // ---- convert + pack + 4x ds_write_b128 (swizzled)
#pragma unroll
    for (int r = 0; r < 4; ++r) {
      union { short8 s; unsigned short u[8]; } pk;
#pragma unroll
      for (int p = 0; p < 8; ++p) {
        float v = (r == 0) ? xv[p].x : (r == 1) ? xv[p].y : (r == 2) ? xv[p].z : xv[p].w;
        pk.u[p] = f2bf(fmaxf(fmaf(v, scv[p], shv[p]), 0.f));
      }
      unsigned addr = ((unsigned)(fragw << 10)) + ((((unsigned)(sub0 + r)) << 4) ^ swz);
      *(short8*)((char*)sXf + addr) = pk.s;
    }
    // ---- prefetch tile t+1 (precedes the barrier: in-place safety)
    if (tt < 1) {
#pragma unroll
      for (int p = 0; p < 8; ++p)
        xv[p] = *(const float4*)(Xb + ((size_t)(cb + p) << 13) + hbase +
                                 (tt + 1) * 64 + hq * 4);
    }
    __syncthreads();

    // ---- MFMA: 8 ds_read_b128 + 32 MFMAs per wave
    f32x4 acc[4][2];
#pragma unroll
    for (int m = 0; m < 4; ++m) {
      acc[m][0] = (f32x4){0.f, 0.f, 0.f, 0.f};
      acc[m][1] = (f32x4){0.f, 0.f, 0.f, 0.f};
    }
#pragma unroll
    for (int k = 0; k < 4; ++k) {
      short8 x0 = *(const short8*)((char*)sXf + (((wh * 2 + 0) * 4 + k) << 10) + br);
      short8 x1 = *(const short8*)((char*)sXf + (((wh * 2 + 1) * 4 + k) << 10) + br);
#pragma unroll
      for (int m = 0; m < 4; ++m) {
        acc[m][0] = __builtin_amdgcn_mfma_f32_16x16x32_bf16(wfr[m][k], x0, acc[m][0], 0, 0, 0);
        acc[m][1] = __builtin_amdgcn_mfma_f32_16x16x32_bf16(wfr[m][k], x1, acc[m][1], 0, 0, 0);
      }
    }

    // ---- epilogue: bias, store f32 [o][h], register stats accumulation
    const int ha = hbase + tt * 64 + wh * 32 + hcol;
#pragma unroll
    for (int m = 0; m < 4; ++m) {
      int obase = wo * 64 + m * 16 + og;
#pragma unroll
      for (int r = 0; r < 4; ++r) {
        int o = obase + r;
        float bv = bias[o];
        float v0 = acc[m][0][r] + bv;
        float v1 = acc[m][1][r] + bv;
        float* po = Ob + ((size_t)o << 13);
        po[ha] = v0;
        po[ha + 16] = v1;
        if (DOSTATS) {
          as_[m][r] += v0 + v1;
          aq_[m][r] = fmaf(v0, v0, fmaf(v1, v1, aq_[m][r]));
        }
      }
    }
    __syncthreads();  // guard LDS reuse by next iteration's ds_write
  }

  if (DOSTATS) {
#pragma unroll
    for (int m = 0; m < 4; ++m) {
#pragma unroll
      for (int r = 0; r < 4; ++r) {
        float s = as_[m][r], q = aq_[m][r];
#pragma unroll
        for (int mm = 1; mm <= 8; mm <<= 1) {
          s += __shfl_xor(s, mm);
          q += __shfl_xor(q, mm);
        }
        if (hcol == 0) {
          int o = wo * 64 + m * 16 + og + r;
          atomicAdd(&ssum[o], s);
          atomicAdd(&ssq[o], q);
        }
      }
    }
    __syncthreads();
    if (t < NC) {
      atomicAdd(&stats[(b * NC + t) * 2], ssum[t]);
      atomicAdd(&stats[(b * NC + t) * 2 + 1], ssq[t]);
    }
  }
}

// ---------------------------------------------------------------------------
extern "C" void kernel_launch(void* const* d_in, const int* in_sizes, int n_in,
                              void* d_out, int out_size, void* d_ws,
                              size_t ws_size, hipStream_t stream) {
  const float* corr = (const float*)d_in[0];
  const float* coh = (const float*)d_in[1];
  const float* feats = (const float*)d_in[2];
  const float* fcw = (const float*)d_in[3];
  const float* fcb = (const float*)d_in[4];
  const float* w1 = (const float*)d_in[5];
  const float* b1 = (const float*)d_in[6];
  const float* g1 = (const float*)d_in[7];
  const float* be1 = (const float*)d_in[8];
  const float* w2 = (const float*)d_in[9];
  const float* b2 = (const float*)d_in[10];
  const float* g2 = (const float*)d_in[11];
  const float* be2 = (const float*)d_in[12];

  float* out = (float*)d_out;  // agg -> x1 -> final output (in-place chain)
  float* ws = (float*)d_ws;
  float* stats1 = ws;             // 4096
  float* stats2 = stats1 + 4096;  // 4096
  float* scale1 = stats2 + 4096;  // 2048
  float* shift1 = scale1 + 2048;  // 2048
  float* scale2 = shift1 + 2048;  // 2048
  float* shift2 = scale2 + 2048;  // 2048

  hipMemsetAsync(stats1, 0, 8192 * sizeof(float), stream);  // stats1+stats2
  alphaagg_kernel<<<1024, 256, 0, stream>>>(corr, coh, feats, fcw, fcb, out,
                                            stats1);
  finalize_kernel<<<1, 128, 0, stream>>>(stats1, g1, be1, scale1, shift1);
  conv_mfma_kernel<true><<<1024, 256, 0, stream>>>(out, scale1, shift1, w1, b1,
                                                   out, stats2);
  finalize_kernel<<<1, 128, 0, stream>>>(stats2, g2, be2, scale2, shift2);
  conv_mfma_kernel<false><<<1024, 256, 0, stream>>>(out, scale2, shift2, w2,
                                                    b2, out, nullptr);
}

// Round 7
// 142.079 us; speedup vs baseline: 1.2532x; 1.2532x over previous
//
#include <hip/hip_runtime.h>

#define NB 16
#define NC 128
#define NH 8192
#define EPSN 1e-5f

typedef __attribute__((ext_vector_type(8))) short short8;
typedef __attribute__((ext_vector_type(4))) float f32x4;

__device__ inline unsigned short f2bf(float f) {
  unsigned int u = __builtin_bit_cast(unsigned int, f);
  u = u + 0x7FFFu + ((u >> 16) & 1u);
  return (unsigned short)(u >> 16);
}

// ---------------------------------------------------------------------------
// alpha[b,h] = sigmoid( sum_v cat(corr,coh)[b,v,h]*fcw[v] + fcb )
// 1024-thread blocks, in-block c-split by 4: thread (csub, px) accumulates 64
// channels for one pixel; LDS reduce over csub; sigmoid; write alpha.
// Grid 512 = 2 blocks/CU x 16 waves -> 32 waves/CU (100% occupancy cap).
__global__ __launch_bounds__(1024) void alpha_kernel(
    const float* __restrict__ corr, const float* __restrict__ coh,
    const float* __restrict__ fcw, const float* __restrict__ fcb,
    float* __restrict__ alpha) {
  __shared__ float part[4][256];
  const int t = threadIdx.x;
  const int b = blockIdx.x >> 5;
  const int h0 = (blockIdx.x & 31) << 8;  // 256-px tile
  const int w = t >> 6;                   // wave 0..15
  const int csub = w >> 2;                // 0..3 (64 virtual channels each)
  const int px = ((w & 3) << 6) + (t & 63);  // 0..255

  const float* base = (csub < 2) ? corr : coh;
  const int c0 = (csub & 1) << 6;
  const float* p = base + ((size_t)(b * NC + c0) << 13) + h0 + px;
  const float* fw = fcw + csub * 64;

  float a0 = 0.f, a1 = 0.f, a2 = 0.f, a3 = 0.f;
#pragma unroll 8
  for (int j = 0; j < 64; j += 4) {
    a0 = fmaf(p[(size_t)(j + 0) << 13], fw[j + 0], a0);
    a1 = fmaf(p[(size_t)(j + 1) << 13], fw[j + 1], a1);
    a2 = fmaf(p[(size_t)(j + 2) << 13], fw[j + 2], a2);
    a3 = fmaf(p[(size_t)(j + 3) << 13], fw[j + 3], a3);
  }
  part[csub][px] = (a0 + a1) + (a2 + a3);
  __syncthreads();
  if (t < 256) {
    float l = (part[0][t] + part[1][t]) + (part[2][t] + part[3][t]) + fcb[0];
    alpha[b * NH + h0 + t] = 1.0f / (1.0f + __expf(-l));
  }
}

// ---------------------------------------------------------------------------
// agg = corr - alpha*feats ; accumulate per-(b,c) sum / sumsq for InstanceNorm1.
__global__ __launch_bounds__(256) void agg_kernel(
    const float* __restrict__ corr, const float* __restrict__ feats,
    const float* __restrict__ alpha, float* __restrict__ agg,
    float* __restrict__ stats) {
  int blk = blockIdx.x;  // B*C*4 = 8192 blocks, 2048 elems each
  int chunk = blk & 3;
  int bc = blk >> 2;
  int b = bc >> 7;
  size_t base = (size_t)bc * NH + chunk * 2048;
  const float* pa = alpha + (size_t)b * NH + chunk * 2048;
  int t = threadIdx.x;
  float s = 0.f, q = 0.f;
#pragma unroll
  for (int r = 0; r < 2; ++r) {
    int off = r * 1024 + t * 4;
    float4 cv = *(const float4*)(corr + base + off);
    float4 fv = *(const float4*)(feats + base + off);
    float4 av = *(const float4*)(pa + off);
    float4 g;
    g.x = cv.x - av.x * fv.x;
    g.y = cv.y - av.y * fv.y;
    g.z = cv.z - av.z * fv.z;
    g.w = cv.w - av.w * fv.w;
    *(float4*)(agg + base + off) = g;
    s += (g.x + g.y) + (g.z + g.w);
    q = fmaf(g.x, g.x, q);
    q = fmaf(g.y, g.y, q);
    q = fmaf(g.z, g.z, q);
    q = fmaf(g.w, g.w, q);
  }
#pragma unroll
  for (int m = 32; m >= 1; m >>= 1) {
    s += __shfl_xor(s, m);
    q += __shfl_xor(q, m);
  }
  __shared__ float red[8];
  int wid = t >> 6;
  if ((t & 63) == 0) {
    red[wid * 2] = s;
    red[wid * 2 + 1] = q;
  }
  __syncthreads();
  if (t == 0) {
    float S = (red[0] + red[2]) + (red[4] + red[6]);
    float Q = (red[1] + red[3]) + (red[5] + red[7]);
    atomicAdd(&stats[bc * 2], S);
    atomicAdd(&stats[bc * 2 + 1], Q);
  }
}

// ---------------------------------------------------------------------------
// Fold IN (per b,c) + analytic BN (per c) + gamma/beta into per-(b,c) affine.
__global__ void finalize_kernel(const float* __restrict__ stats,
                                const float* __restrict__ g,
                                const float* __restrict__ be,
                                float* __restrict__ scale,
                                float* __restrict__ shift) {
  int c = threadIdx.x;  // 128 threads, 1 block
  float mean[NB], rstd[NB];
  float bnacc = 0.f;
#pragma unroll
  for (int b = 0; b < NB; ++b) {
    float s = stats[(b * NC + c) * 2];
    float q = stats[(b * NC + c) * 2 + 1];
    float m = s * (1.f / NH);
    float v = fmaxf(q * (1.f / NH) - m * m, 0.f);
    float r = rsqrtf(v + EPSN);
    mean[b] = m;
    rstd[b] = r;
    bnacc += v * r * r;
  }
  float bnr = rsqrtf(bnacc * (1.f / NB) + EPSN);
  float gc = g[c], bec = be[c];
#pragma unroll
  for (int b = 0; b < NB; ++b) {
    float sc = rstd[b] * bnr * gc;
    scale[b * NC + c] = sc;
    shift[b * NC + c] = fmaf(-mean[b], sc, bec);
  }
}

// ---------------------------------------------------------------------------
// bf16-MFMA 1x1 conv with fused input affine+ReLU, tile-looped + pipelined.
//   Out[b,o,h] = sum_c relu(X[b,c,h]*scale[b,c]+shift[b,c]) * W[o,c] + bias[o]
// LDS layout (B-fragment order):
//   halfword idx = fragid*512 + sublane*8 + j
//   fragid = (h>>4)*4 + (c>>5), sublane = 16*((c>>3)&3) + (h&15), j = c&7
// XOR swizzle byte ^= ((byte>>7)&7)<<4 on BOTH ds_write and ds_read.
// Block = (b, 2 consecutive 64-h tiles). In-place safe: each block reads and
// writes only its own disjoint h-range.
template <bool DOSTATS>
__global__ __launch_bounds__(256) void conv_mfma_kernel(
    const float* X, const float* __restrict__ scale,
    const float* __restrict__ shift, const float* __restrict__ W,
    const float* __restrict__ bias, float* Out, float* __restrict__ stats) {
  __shared__ __align__(16) unsigned short sXf[8192];  // 16 frags x 1 KB
  __shared__ float ssum[NC], ssq[NC];
  const int t = threadIdx.x;
  const int b = blockIdx.x >> 6;             // 64 blocks per batch
  const int hbase = (blockIdx.x & 63) << 7;  // 128 h per block (2 tiles)
  const int lane = t & 63;
  const int wv = t >> 6;
  const int wo = wv >> 1;  // o-half: wo*64
  const int wh = wv & 1;   // h-half within tile: wh*32

  if (DOSTATS && t < NC) { ssum[t] = 0.f; ssq[t] = 0.f; }

  // staging ownership: 8 consecutive c x 4 consecutive h per thread
  const int cb = (t >> 4) << 3;  // 0,8,...,120
  const int hq = t & 15;         // local h = hq*4 + r
  const int fragw = ((hq >> 2) << 2) + (cb >> 5);
  const int sub0 = (((cb >> 3) & 3) << 4) + ((hq & 3) << 2);
  const unsigned swz = ((unsigned)(sub0 >> 3)) << 4;  // r-invariant
  const unsigned br = ((unsigned)(lane << 4)) ^ (((unsigned)(lane >> 3)) << 4);

  const float* Xb = X + ((size_t)(b * NC) << 13);
  float* Ob = Out + ((size_t)(b * NC) << 13);

  // ---- prologue: issue tile-0 loads first (critical path)
  float4 xv[8];
#pragma unroll
  for (int p = 0; p < 8; ++p)
    xv[p] = *(const float4*)(Xb + ((size_t)(cb + p) << 13) + hbase + hq * 4);

  float scv[8], shv[8];
#pragma unroll
  for (int p = 0; p < 8; ++p) {
    scv[p] = scale[b * NC + cb + p];
    shv[p] = shift[b * NC + cb + p];
  }

  // ---- W frags (A operand), loaded once per block
  short8 wfr[4][4];
  {
    const int orow = wo * 64 + (lane & 15);
    const int cbw = 8 * (lane >> 4);
#pragma unroll
    for (int m = 0; m < 4; ++m) {
#pragma unroll
      for (int k = 0; k < 4; ++k) {
        const float* p = W + (orow + m * 16) * NC + k * 32 + cbw;
        float4 lo = *(const float4*)p;
        float4 hi = *(const float4*)(p + 4);
        union { short8 s; unsigned short u[8]; } fr;
        fr.u[0] = f2bf(lo.x); fr.u[1] = f2bf(lo.y);
        fr.u[2] = f2bf(lo.z); fr.u[3] = f2bf(lo.w);
        fr.u[4] = f2bf(hi.x); fr.u[5] = f2bf(hi.y);
        fr.u[6] = f2bf(hi.z); fr.u[7] = f2bf(hi.w);
        wfr[m][k] = fr.s;
      }
    }
  }

  float as_[4][4], aq_[4][4];
  if (DOSTATS) {
#pragma unroll
    for (int m = 0; m < 4; ++m)
#pragma unroll
      for (int r = 0; r < 4; ++r) { as_[m][r] = 0.f; aq_[m][r] = 0.f; }
  }

  const int og = (lane >> 4) << 2;
  const int hcol = lane & 15;

  for (int tt = 0; tt < 2; ++tt) {
    // ---- convert + pack + 4x ds_write_b128 (swizzled)
#pragma unroll
    for (int r = 0; r < 4; ++r) {
      union { short8 s; unsigned short u[8]; } pk;
#pragma unroll
      for (int p = 0; p < 8; ++p) {
        float v = (r == 0) ? xv[p].x : (r == 1) ? xv[p].y : (r == 2) ? xv[p].z : xv[p].w;
        pk.u[p] = f2bf(fmaxf(fmaf(v, scv[p], shv[p]), 0.f));
      }
      unsigned addr = ((unsigned)(fragw << 10)) + ((((unsigned)(sub0 + r)) << 4) ^ swz);
      *(short8*)((char*)sXf + addr) = pk.s;
    }
    // ---- prefetch tile t+1 (precedes the barrier: in-place safety)
    if (tt < 1) {
#pragma unroll
      for (int p = 0; p < 8; ++p)
        xv[p] = *(const float4*)(Xb + ((size_t)(cb + p) << 13) + hbase +
                                 (tt + 1) * 64 + hq * 4);
    }
    __syncthreads();

    // ---- MFMA: 8 ds_read_b128 + 32 MFMAs per wave
    f32x4 acc[4][2];
#pragma unroll
    for (int m = 0; m < 4; ++m) {
      acc[m][0] = (f32x4){0.f, 0.f, 0.f, 0.f};
      acc[m][1] = (f32x4){0.f, 0.f, 0.f, 0.f};
    }
#pragma unroll
    for (int k = 0; k < 4; ++k) {
      short8 x0 = *(const short8*)((char*)sXf + (((wh * 2 + 0) * 4 + k) << 10) + br);
      short8 x1 = *(const short8*)((char*)sXf + (((wh * 2 + 1) * 4 + k) << 10) + br);
#pragma unroll
      for (int m = 0; m < 4; ++m) {
        acc[m][0] = __builtin_amdgcn_mfma_f32_16x16x32_bf16(wfr[m][k], x0, acc[m][0], 0, 0, 0);
        acc[m][1] = __builtin_amdgcn_mfma_f32_16x16x32_bf16(wfr[m][k], x1, acc[m][1], 0, 0, 0);
      }
    }

    // ---- epilogue: bias, store f32 [o][h], register stats accumulation
    const int ha = hbase + tt * 64 + wh * 32 + hcol;
#pragma unroll
    for (int m = 0; m < 4; ++m) {
      int obase = wo * 64 + m * 16 + og;
#pragma unroll
      for (int r = 0; r < 4; ++r) {
        int o = obase + r;
        float bv = bias[o];
        float v0 = acc[m][0][r] + bv;
        float v1 = acc[m][1][r] + bv;
        float* po = Ob + ((size_t)o << 13);
        po[ha] = v0;
        po[ha + 16] = v1;
        if (DOSTATS) {
          as_[m][r] += v0 + v1;
          aq_[m][r] = fmaf(v0, v0, fmaf(v1, v1, aq_[m][r]));
        }
      }
    }
    __syncthreads();  // guard LDS reuse by next iteration's ds_write
  }

  if (DOSTATS) {
#pragma unroll
    for (int m = 0; m < 4; ++m) {
#pragma unroll
      for (int r = 0; r < 4; ++r) {
        float s = as_[m][r], q = aq_[m][r];
#pragma unroll
        for (int mm = 1; mm <= 8; mm <<= 1) {
          s += __shfl_xor(s, mm);
          q += __shfl_xor(q, mm);
        }
        if (hcol == 0) {
          int o = wo * 64 + m * 16 + og + r;
          atomicAdd(&ssum[o], s);
          atomicAdd(&ssq[o], q);
        }
      }
    }
    __syncthreads();
    if (t < NC) {
      atomicAdd(&stats[(b * NC + t) * 2], ssum[t]);
      atomicAdd(&stats[(b * NC + t) * 2 + 1], ssq[t]);
    }
  }
}

// ---------------------------------------------------------------------------
extern "C" void kernel_launch(void* const* d_in, const int* in_sizes, int n_in,
                              void* d_out, int out_size, void* d_ws,
                              size_t ws_size, hipStream_t stream) {
  const float* corr = (const float*)d_in[0];
  const float* coh = (const float*)d_in[1];
  const float* feats = (const float*)d_in[2];
  const float* fcw = (const float*)d_in[3];
  const float* fcb = (const float*)d_in[4];
  const float* w1 = (const float*)d_in[5];
  const float* b1 = (const float*)d_in[6];
  const float* g1 = (const float*)d_in[7];
  const float* be1 = (const float*)d_in[8];
  const float* w2 = (const float*)d_in[9];
  const float* b2 = (const float*)d_in[10];
  const float* g2 = (const float*)d_in[11];
  const float* be2 = (const float*)d_in[12];

  float* out = (float*)d_out;  // agg -> x1 -> final output (in-place chain)
  float* ws = (float*)d_ws;
  float* alphab = ws;               // 131072
  float* stats1 = alphab + 131072;  // 4096
  float* stats2 = stats1 + 4096;    // 4096
  float* scale1 = stats2 + 4096;    // 2048
  float* shift1 = scale1 + 2048;    // 2048
  float* scale2 = shift1 + 2048;    // 2048
  float* shift2 = scale2 + 2048;    // 2048

  hipMemsetAsync(stats1, 0, 8192 * sizeof(float), stream);  // stats1+stats2
  alpha_kernel<<<512, 1024, 0, stream>>>(corr, coh, fcw, fcb, alphab);
  agg_kernel<<<8192, 256, 0, stream>>>(corr, feats, alphab, out, stats1);
  finalize_kernel<<<1, 128, 0, stream>>>(stats1, g1, be1, scale1, shift1);
  conv_mfma_kernel<true><<<1024, 256, 0, stream>>>(out, scale1, shift1, w1, b1,
                                                   out, stats2);
  finalize_kernel<<<1, 128, 0, stream>>>(stats2, g2, be2, scale2, shift2);
  conv_mfma_kernel<false><<<1024, 256, 0, stream>>>(out, scale2, shift2, w2,
                                                    b2, out, nullptr);
}

// Round 8
// 131.674 us; speedup vs baseline: 1.3522x; 1.0790x over previous
//
#include <hip/hip_runtime.h>

#define NB 16
#define NC 128
#define NH 8192
#define EPSN 1e-5f

typedef __attribute__((ext_vector_type(8))) short short8;
typedef __attribute__((ext_vector_type(4))) float f32x4;

__device__ inline unsigned short f2bf(float f) {
  unsigned int u = __builtin_bit_cast(unsigned int, f);
  u = u + 0x7FFFu + ((u >> 16) & 1u);
  return (unsigned short)(u >> 16);
}

// ---------------------------------------------------------------------------
// alpha[b,h] = sigmoid( sum_v cat(corr,coh)[b,v,h]*fcw[v] + fcb )
// Block = 256 threads = (csub 0..7) x (32 pixel-quads = 128 px).
// Each thread: 32 float4 loads (its 32 channels, fully unrolled), 4 float4
// accumulators, fcw preloaded to registers. LDS reduce over csub, sigmoid.
// Grid = B*NH/128 = 1024 blocks (4 waves each) -> high TLP + 16B/lane loads.
__global__ __launch_bounds__(256) void alpha_kernel(
    const float* __restrict__ corr, const float* __restrict__ coh,
    const float* __restrict__ fcw, const float* __restrict__ fcb,
    float* __restrict__ alpha) {
  __shared__ float part[8][128];
  const int t = threadIdx.x;
  const int b = blockIdx.x >> 6;
  const int h0 = (blockIdx.x & 63) << 7;  // 128-px tile
  const int csub = t >> 5;                // 0..7 (32 virtual channels each)
  const int quad = t & 31;                // pixel-quad: px = quad*4

  const float* base = (csub < 4) ? corr : coh;
  const int c0 = (csub & 3) << 5;
  const float* p = base + ((size_t)(b * NC + c0) << 13) + h0 + quad * 4;

  // fcw[csub*32 + j] for j=0..31 (csub>=4 -> fcw[128+...] automatically)
  float4 fw4[8];
#pragma unroll
  for (int k = 0; k < 8; ++k)
    fw4[k] = *(const float4*)(fcw + csub * 32 + k * 4);

  float4 a0 = {0, 0, 0, 0}, a1 = {0, 0, 0, 0}, a2 = {0, 0, 0, 0},
         a3 = {0, 0, 0, 0};
#pragma unroll
  for (int j = 0; j < 32; ++j) {
    float4 v = *(const float4*)(p + ((size_t)j << 13));
    float w = (j & 3) == 0   ? fw4[j >> 2].x
              : (j & 3) == 1 ? fw4[j >> 2].y
              : (j & 3) == 2 ? fw4[j >> 2].z
                             : fw4[j >> 2].w;
    float4& a = (j & 3) == 0 ? a0 : (j & 3) == 1 ? a1 : (j & 3) == 2 ? a2 : a3;
    a.x = fmaf(v.x, w, a.x);
    a.y = fmaf(v.y, w, a.y);
    a.z = fmaf(v.z, w, a.z);
    a.w = fmaf(v.w, w, a.w);
  }
  float4 s;
  s.x = (a0.x + a1.x) + (a2.x + a3.x);
  s.y = (a0.y + a1.y) + (a2.y + a3.y);
  s.z = (a0.z + a1.z) + (a2.z + a3.z);
  s.w = (a0.w + a1.w) + (a2.w + a3.w);
  *(float4*)&part[csub][quad * 4] = s;
  __syncthreads();
  if (t < 128) {
    float l = fcb[0];
#pragma unroll
    for (int pidx = 0; pidx < 8; ++pidx) l += part[pidx][t];
    alpha[b * NH + h0 + t] = 1.0f / (1.0f + __expf(-l));
  }
}

// ---------------------------------------------------------------------------
// agg = corr - alpha*feats ; accumulate per-(b,c) sum / sumsq for InstanceNorm1.
__global__ __launch_bounds__(256) void agg_kernel(
    const float* __restrict__ corr, const float* __restrict__ feats,
    const float* __restrict__ alpha, float* __restrict__ agg,
    float* __restrict__ stats) {
  int blk = blockIdx.x;  // B*C*4 = 8192 blocks, 2048 elems each
  int chunk = blk & 3;
  int bc = blk >> 2;
  int b = bc >> 7;
  size_t base = (size_t)bc * NH + chunk * 2048;
  const float* pa = alpha + (size_t)b * NH + chunk * 2048;
  int t = threadIdx.x;
  float s = 0.f, q = 0.f;
#pragma unroll
  for (int r = 0; r < 2; ++r) {
    int off = r * 1024 + t * 4;
    float4 cv = *(const float4*)(corr + base + off);
    float4 fv = *(const float4*)(feats + base + off);
    float4 av = *(const float4*)(pa + off);
    float4 g;
    g.x = cv.x - av.x * fv.x;
    g.y = cv.y - av.y * fv.y;
    g.z = cv.z - av.z * fv.z;
    g.w = cv.w - av.w * fv.w;
    *(float4*)(agg + base + off) = g;
    s += (g.x + g.y) + (g.z + g.w);
    q = fmaf(g.x, g.x, q);
    q = fmaf(g.y, g.y, q);
    q = fmaf(g.z, g.z, q);
    q = fmaf(g.w, g.w, q);
  }
#pragma unroll
  for (int m = 32; m >= 1; m >>= 1) {
    s += __shfl_xor(s, m);
    q += __shfl_xor(q, m);
  }
  __shared__ float red[8];
  int wid = t >> 6;
  if ((t & 63) == 0) {
    red[wid * 2] = s;
    red[wid * 2 + 1] = q;
  }
  __syncthreads();
  if (t == 0) {
    float S = (red[0] + red[2]) + (red[4] + red[6]);
    float Q = (red[1] + red[3]) + (red[5] + red[7]);
    atomicAdd(&stats[bc * 2], S);
    atomicAdd(&stats[bc * 2 + 1], Q);
  }
}

// ---------------------------------------------------------------------------
// Fold IN (per b,c) + analytic BN (per c) + gamma/beta into per-(b,c) affine.
__global__ void finalize_kernel(const float* __restrict__ stats,
                                const float* __restrict__ g,
                                const float* __restrict__ be,
                                float* __restrict__ scale,
                                float* __restrict__ shift) {
  int c = threadIdx.x;  // 128 threads, 1 block
  float mean[NB], rstd[NB];
  float bnacc = 0.f;
#pragma unroll
  for (int b = 0; b < NB; ++b) {
    float s = stats[(b * NC + c) * 2];
    float q = stats[(b * NC + c) * 2 + 1];
    float m = s * (1.f / NH);
    float v = fmaxf(q * (1.f / NH) - m * m, 0.f);
    float r = rsqrtf(v + EPSN);
    mean[b] = m;
    rstd[b] = r;
    bnacc += v * r * r;
  }
  float bnr = rsqrtf(bnacc * (1.f / NB) + EPSN);
  float gc = g[c], bec = be[c];
#pragma unroll
  for (int b = 0; b < NB; ++b) {
    float sc = rstd[b] * bnr * gc;
    scale[b * NC + c] = sc;
    shift[b * NC + c] = fmaf(-mean[b], sc, bec);
  }
}

// ---------------------------------------------------------------------------
// bf16-MFMA 1x1 conv with fused input affine+ReLU, tile-looped + pipelined.
//   Out[b,o,h] = sum_c relu(X[b,c,h]*scale[b,c]+shift[b,c]) * W[o,c] + bias[o]
// LDS layout (B-fragment order):
//   halfword idx = fragid*512 + sublane*8 + j
//   fragid = (h>>4)*4 + (c>>5), sublane = 16*((c>>3)&3) + (h&15), j = c&7
// XOR swizzle byte ^= ((byte>>7)&7)<<4 on BOTH ds_write and ds_read.
// Block = (b, 2 consecutive 64-h tiles). In-place safe: each block reads and
// writes only its own disjoint h-range.
template <bool DOSTATS>
__global__ __launch_bounds__(256) void conv_mfma_kernel(
    const float* X, const float* __restrict__ scale,
    const float* __restrict__ shift, const float* __restrict__ W,
    const float* __restrict__ bias, float* Out, float* __restrict__ stats) {
  __shared__ __align__(16) unsigned short sXf[8192];  // 16 frags x 1 KB
  __shared__ float ssum[NC], ssq[NC];
  const int t = threadIdx.x;
  const int b = blockIdx.x >> 6;             // 64 blocks per batch
  const int hbase = (blockIdx.x & 63) << 7;  // 128 h per block (2 tiles)
  const int lane = t & 63;
  const int wv = t >> 6;
  const int wo = wv >> 1;  // o-half: wo*64
  const int wh = wv & 1;   // h-half within tile: wh*32

  if (DOSTATS && t < NC) { ssum[t] = 0.f; ssq[t] = 0.f; }

  // staging ownership: 8 consecutive c x 4 consecutive h per thread
  const int cb = (t >> 4) << 3;  // 0,8,...,120
  const int hq = t & 15;         // local h = hq*4 + r
  const int fragw = ((hq >> 2) << 2) + (cb >> 5);
  const int sub0 = (((cb >> 3) & 3) << 4) + ((hq & 3) << 2);
  const unsigned swz = ((unsigned)(sub0 >> 3)) << 4;  // r-invariant
  const unsigned br = ((unsigned)(lane << 4)) ^ (((unsigned)(lane >> 3)) << 4);

  const float* Xb = X + ((size_t)(b * NC) << 13);
  float* Ob = Out + ((size_t)(b * NC) << 13);

  // ---- prologue: issue tile-0 loads first (critical path)
  float4 xv[8];
#pragma unroll
  for (int p = 0; p < 8; ++p)
    xv[p] = *(const float4*)(Xb + ((size_t)(cb + p) << 13) + hbase + hq * 4);

  float scv[8], shv[8];
#pragma unroll
  for (int p = 0; p < 8; ++p) {
    scv[p] = scale[b * NC + cb + p];
    shv[p] = shift[b * NC + cb + p];
  }

  // ---- W frags (A operand), loaded once per block
  short8 wfr[4][4];
  {
    const int orow = wo * 64 + (lane & 15);
    const int cbw = 8 * (lane >> 4);
#pragma unroll
    for (int m = 0; m < 4; ++m) {
#pragma unroll
      for (int k = 0; k < 4; ++k) {
        const float* p = W + (orow + m * 16) * NC + k * 32 + cbw;
        float4 lo = *(const float4*)p;
        float4 hi = *(const float4*)(p + 4);
        union { short8 s; unsigned short u[8]; } fr;
        fr.u[0] = f2bf(lo.x); fr.u[1] = f2bf(lo.y);
        fr.u[2] = f2bf(lo.z); fr.u[3] = f2bf(lo.w);
        fr.u[4] = f2bf(hi.x); fr.u[5] = f2bf(hi.y);
        fr.u[6] = f2bf(hi.z); fr.u[7] = f2bf(hi.w);
        wfr[m][k] = fr.s;
      }
    }
  }

  float as_[4][4], aq_[4][4];
  if (DOSTATS) {
#pragma unroll
    for (int m = 0; m < 4; ++m)
#pragma unroll
      for (int r = 0; r < 4; ++r) { as_[m][r] = 0.f; aq_[m][r] = 0.f; }
  }

  const int og = (lane >> 4) << 2;
  const int hcol = lane & 15;

  for (int tt = 0; tt < 2; ++tt) {
    // ---- convert + pack + 4x ds_write_b128 (swizzled)
#pragma unroll
    for (int r = 0; r < 4; ++r) {
      union { short8 s; unsigned short u[8]; } pk;
#pragma unroll
      for (int p = 0; p < 8; ++p) {
        float v = (r == 0) ? xv[p].x : (r == 1) ? xv[p].y : (r == 2) ? xv[p].z : xv[p].w;
        pk.u[p] = f2bf(fmaxf(fmaf(v, scv[p], shv[p]), 0.f));
      }
      unsigned addr = ((unsigned)(fragw << 10)) + ((((unsigned)(sub0 + r)) << 4) ^ swz);
      *(short8*)((char*)sXf + addr) = pk.s;
    }
    // ---- prefetch tile t+1 (precedes the barrier: in-place safety)
    if (tt < 1) {
#pragma unroll
      for (int p = 0; p < 8; ++p)
        xv[p] = *(const float4*)(Xb + ((size_t)(cb + p) << 13) + hbase +
                                 (tt + 1) * 64 + hq * 4);
    }
    __syncthreads();

    // ---- MFMA: 8 ds_read_b128 + 32 MFMAs per wave
    f32x4 acc[4][2];
#pragma unroll
    for (int m = 0; m < 4; ++m) {
      acc[m][0] = (f32x4){0.f, 0.f, 0.f, 0.f};
      acc[m][1] = (f32x4){0.f, 0.f, 0.f, 0.f};
    }
#pragma unroll
    for (int k = 0; k < 4; ++k) {
      short8 x0 = *(const short8*)((char*)sXf + (((wh * 2 + 0) * 4 + k) << 10) + br);
      short8 x1 = *(const short8*)((char*)sXf + (((wh * 2 + 1) * 4 + k) << 10) + br);
#pragma unroll
      for (int m = 0; m < 4; ++m) {
        acc[m][0] = __builtin_amdgcn_mfma_f32_16x16x32_bf16(wfr[m][k], x0, acc[m][0], 0, 0, 0);
        acc[m][1] = __builtin_amdgcn_mfma_f32_16x16x32_bf16(wfr[m][k], x1, acc[m][1], 0, 0, 0);
      }
    }

    // ---- epilogue: bias, store f32 [o][h], register stats accumulation
    const int ha = hbase + tt * 64 + wh * 32 + hcol;
#pragma unroll
    for (int m = 0; m < 4; ++m) {
      int obase = wo * 64 + m * 16 + og;
#pragma unroll
      for (int r = 0; r < 4; ++r) {
        int o = obase + r;
        float bv = bias[o];
        float v0 = acc[m][0][r] + bv;
        float v1 = acc[m][1][r] + bv;
        float* po = Ob + ((size_t)o << 13);
        po[ha] = v0;
        po[ha + 16] = v1;
        if (DOSTATS) {
          as_[m][r] += v0 + v1;
          aq_[m][r] = fmaf(v0, v0, fmaf(v1, v1, aq_[m][r]));
        }
      }
    }
    __syncthreads();  // guard LDS reuse by next iteration's ds_write
  }

  if (DOSTATS) {
#pragma unroll
    for (int m = 0; m < 4; ++m) {
#pragma unroll
      for (int r = 0; r < 4; ++r) {
        float s = as_[m][r], q = aq_[m][r];
#pragma unroll
        for (int mm = 1; mm <= 8; mm <<= 1) {
          s += __shfl_xor(s, mm);
          q += __shfl_xor(q, mm);
        }
        if (hcol == 0) {
          int o = wo * 64 + m * 16 + og + r;
          atomicAdd(&ssum[o], s);
          atomicAdd(&ssq[o], q);
        }
      }
    }
    __syncthreads();
    if (t < NC) {
      atomicAdd(&stats[(b * NC + t) * 2], ssum[t]);
      atomicAdd(&stats[(b * NC + t) * 2 + 1], ssq[t]);
    }
  }
}

// ---------------------------------------------------------------------------
extern "C" void kernel_launch(void* const* d_in, const int* in_sizes, int n_in,
                              void* d_out, int out_size, void* d_ws,
                              size_t ws_size, hipStream_t stream) {
  const float* corr = (const float*)d_in[0];
  const float* coh = (const float*)d_in[1];
  const float* feats = (const float*)d_in[2];
  const float* fcw = (const float*)d_in[3];
  const float* fcb = (const float*)d_in[4];
  const float* w1 = (const float*)d_in[5];
  const float* b1 = (const float*)d_in[6];
  const float* g1 = (const float*)d_in[7];
  const float* be1 = (const float*)d_in[8];
  const float* w2 = (const float*)d_in[9];
  const float* b2 = (const float*)d_in[10];
  const float* g2 = (const float*)d_in[11];
  const float* be2 = (const float*)d_in[12];

  float* out = (float*)d_out;  // agg -> x1 -> final output (in-place chain)
  float* ws = (float*)d_ws;
  float* alphab = ws;               // 131072
  float* stats1 = alphab + 131072;  // 4096
  float* stats2 = stats1 + 4096;    // 4096
  float* scale1 = stats2 + 4096;    // 2048
  float* shift1 = scale1 + 2048;    // 2048
  float* scale2 = shift1 + 2048;    // 2048
  float* shift2 = scale2 + 2048;    // 2048

  hipMemsetAsync(stats1, 0, 8192 * sizeof(float), stream);  // stats1+stats2
  alpha_kernel<<<1024, 256, 0, stream>>>(corr, coh, fcw, fcb, alphab);
  agg_kernel<<<8192, 256, 0, stream>>>(corr, feats, alphab, out, stats1);
  finalize_kernel<<<1, 128, 0, stream>>>(stats1, g1, be1, scale1, shift1);
  conv_mfma_kernel<true><<<1024, 256, 0, stream>>>(out, scale1, shift1, w1, b1,
                                                   out, stats2);
  finalize_kernel<<<1, 128, 0, stream>>>(stats2, g2, be2, scale2, shift2);
  conv_mfma_kernel<false><<<1024, 256, 0, stream>>>(out, scale2, shift2, w2,
                                                    b2, out, nullptr);
}